// Round 11
// baseline (1432.631 us; speedup 1.0000x reference)
//
#include <hip/hip_runtime.h>
#include <math.h>

typedef short bf16x8 __attribute__((ext_vector_type(8)));
typedef float f32x4 __attribute__((ext_vector_type(4)));

#define GLL16(g, l) \
  __builtin_amdgcn_global_load_lds((__attribute__((address_space(1))) const unsigned int*)(g), \
                                   (__attribute__((address_space(3))) unsigned int*)(l), 16, 0, 0)

// ---------- helpers ----------
__device__ __forceinline__ float wsum(float v){
  #pragma unroll
  for (int o=32;o;o>>=1) v += __shfl_xor(v,o);
  return v;
}
__device__ __forceinline__ float geluf(float x){
  return 0.5f*x*(1.0f+erff(x*0.7071067811865475f));
}
__device__ __forceinline__ short fbf(float f){
  unsigned u = __float_as_uint(f);
  unsigned r = (u + 0x7fffu + ((u>>16)&1u)) >> 16;
  return (short)r;
}
__device__ __forceinline__ float bff(short s){
  return __uint_as_float(((unsigned)(unsigned short)s)<<16);
}
__device__ __forceinline__ unsigned fkey(float f){
  unsigned b=__float_as_uint(f);
  return (b&0x80000000u)? ~b : (b|0x80000000u);
}
__device__ __forceinline__ float fdec(unsigned k){
  unsigned b=(k&0x80000000u)? (k&0x7fffffffu) : ~k;
  return __uint_as_float(b);
}

// ---------- mask bit packing (dtype decided on HOST via in_sizes) ----------
__global__ void mask_bits_kernel(const void* __restrict__ m, unsigned long long* __restrict__ mb,
                                 long long nOut, int mode){
  long long i = (long long)blockIdx.x*256 + threadIdx.x;
  if (i>=nOut) return;
  unsigned long long bits = 0;
  if (mode){ // byte input
    const unsigned long long* p = (const unsigned long long*)((const unsigned char*)m + i*64);
    #pragma unroll
    for (int k=0;k<8;k++){
      unsigned long long v = p[k];
      #pragma unroll
      for (int b=0;b<8;b++)
        bits |= (unsigned long long)(((v>>(b*8))&0xffull)!=0) << (k*8+b);
    }
  } else { // int input
    const int4* p = (const int4*)((const int*)m + i*64);
    #pragma unroll
    for (int k=0;k<16;k++){
      int4 v = p[k];
      bits |= (unsigned long long)(v.x!=0) << (k*4+0);
      bits |= (unsigned long long)(v.y!=0) << (k*4+1);
      bits |= (unsigned long long)(v.z!=0) << (k*4+2);
      bits |= (unsigned long long)(v.w!=0) << (k*4+3);
    }
  }
  mb[i] = bits;
}

__device__ __forceinline__ float epi(float v, const float* bias, int col, int act){
  if (bias) v += bias[col];
  if (act==1) v = geluf(v);
  else if (act==2) v = v*(1.f/(1.f+__expf(-1.702f*v)));
  return v;
}

// ---------- bf16 MFMA GEMM, 128x128 tile, BK=32 ----------
#define XBM 128
#define XBN 128
#define XBK 32
__global__ __launch_bounds__(256)
void gemm_bf16_big(const short* __restrict__ A, int lda, long long sA,
                   const short* __restrict__ B, int ldb, long long sB,
                   const float* __restrict__ bias, long long sBias,
                   const float* __restrict__ res, int ldr, long long sR,
                   void* __restrict__ out, int ldo, long long sO, int outbf16,
                   int M, int N, int K, int act, int KS)
{
  __shared__ short As[XBM*XBK];
  __shared__ short Bs[XBN*XBK];
  int zz = blockIdx.z;
  int z = zz / KS, ks = zz - z*KS;
  A += (long long)z*sA; B += (long long)z*sB;
  if (res) res += (long long)z*sR;
  if (bias) bias += (long long)z*sBias;
  float* outF = (float*)out + (long long)z*sO;
  short* outH = (short*)out + (long long)z*sO;

  int tid = threadIdx.x;
  int rowBase = blockIdx.y*XBM;
  int colBase = blockIdx.x*XBN;

  int Kc = ((K + KS*XBK - 1)/(KS*XBK))*XBK;
  int kbeg = ks*Kc;
  int kend = min(K, kbeg+Kc);
  if (kbeg >= kend) return;

  int w = tid>>6;
  int lane = tid&63;
  int lm = lane&15, quad = lane>>4;
  int waveM = w>>1, waveN = w&1;

  int arow0 = min(rowBase + w*32 + lm,      M-1);
  int arow1 = min(rowBase + w*32 + 16 + lm, M-1);
  int brow0 = min(colBase + w*32 + lm,      N-1);
  int brow1 = min(colBase + w*32 + 16 + lm, N-1);
  const short* Ag0 = A + (long long)arow0*lda + quad*8;
  const short* Ag1 = A + (long long)arow1*lda + quad*8;
  const short* Bg0 = B + (long long)brow0*ldb + quad*8;
  const short* Bg1 = B + (long long)brow1*ldb + quad*8;
  short* Al0 = &As[(w*2+0)*512];
  short* Al1 = &As[(w*2+1)*512];
  short* Bl0 = &Bs[(w*2+0)*512];
  short* Bl1 = &Bs[(w*2+1)*512];

  f32x4 acc[4][4] = {};

  for (int k0=kbeg; k0<kend; k0+=XBK){
    GLL16(Ag0 + k0, Al0);
    GLL16(Ag1 + k0, Al1);
    GLL16(Bg0 + k0, Bl0);
    GLL16(Bg1 + k0, Bl1);
    __syncthreads();
    bf16x8 af[4], bfr[4];
    #pragma unroll
    for (int tm=0;tm<4;tm++) af[tm]  = *(bf16x8*)&As[(waveM*4+tm)*512 + quad*128 + lm*8];
    #pragma unroll
    for (int tn=0;tn<4;tn++) bfr[tn] = *(bf16x8*)&Bs[(waveN*4+tn)*512 + quad*128 + lm*8];
    #pragma unroll
    for (int tm=0;tm<4;tm++)
      #pragma unroll
      for (int tn=0;tn<4;tn++)
        acc[tm][tn] = __builtin_amdgcn_mfma_f32_16x16x32_bf16(af[tm], bfr[tn], acc[tm][tn], 0,0,0);
    __syncthreads();
  }

  #pragma unroll
  for (int tm=0;tm<4;tm++){
    #pragma unroll
    for (int tn=0;tn<4;tn++){
      int col = colBase + waveN*64 + tn*16 + lm;
      if (col>=N) continue;
      #pragma unroll
      for (int reg=0;reg<4;reg++){
        int row = rowBase + waveM*64 + tm*16 + quad*4 + reg;
        if (row>=M) continue;
        float v = acc[tm][tn][reg];
        if (KS>1){ atomicAdd(&outF[(long long)row*ldo+col], v); continue; }
        v = epi(v, bias, col, act);
        if (res) v += res[(long long)row*ldr+col];
        if (outbf16) outH[(long long)row*ldo+col] = fbf(v);
        else         outF[(long long)row*ldo+col] = v;
      }
    }
  }
}

// ---------- bf16 MFMA GEMM, 64x64 tile, BK=64 ----------
// outbf16==3: scatter epilogue (segment sum/max/count) — out not written
// out2: secondary bf16 copy of f32 output. aDiv: A advances every aDiv z.
// bMod: B advances by (z % bMod)*sB (0 => z*sB). rbias: per-ROW bias, advanced (z/aDiv)*sRbias.
__global__ __launch_bounds__(256)
void gemm_bf16_s(const short* __restrict__ A, int lda, long long sA, int aDiv,
                 const short* __restrict__ B, int ldb, long long sB, int bMod,
                 const float* __restrict__ bias, long long sBias,
                 const float* __restrict__ rbias, long long sRbias,
                 const float* __restrict__ res, int ldr, long long sR,
                 void* __restrict__ out, int ldo, long long sO, int outbf16,
                 int M, int N, int K, int act, short* __restrict__ out2,
                 const int* __restrict__ sgi, float* __restrict__ ssum,
                 unsigned* __restrict__ smax, float* __restrict__ scnt)
{
  __shared__ short As[64*64];   // [4 row-groups][2 k-halves][512] lane-order
  __shared__ short Bs[64*64];
  int z = blockIdx.z;
  A += (long long)(z/aDiv)*sA;
  int zb = bMod ? (z % bMod) : z;
  B += (long long)zb*sB;
  if (res) res += (long long)z*sR;
  if (bias) bias += (long long)z*sBias;
  if (rbias) rbias += (long long)(z/aDiv)*sRbias;
  float* outF = (float*)out + (long long)z*sO;
  short* outH = (short*)out + (long long)z*sO;

  int tid = threadIdx.x;
  int rowBase = blockIdx.y*64;
  int colBase = blockIdx.x*64;

  int w = tid>>6;
  int lane = tid&63;
  int lm = lane&15, quad = lane>>4;
  int wm = w>>1, wn = w&1;

  int arow = min(rowBase + w*16 + lm, M-1);
  int brow = min(colBase + w*16 + lm, N-1);
  const short* Ag = A + (long long)arow*lda + quad*8;
  const short* Bg = B + (long long)brow*ldb + quad*8;
  short* Al = &As[w*1024];
  short* Bl = &Bs[w*1024];

  f32x4 acc[2][2] = {};

  for (int k0=0; k0<K; k0+=64){
    GLL16(Ag + k0,      Al);
    GLL16(Ag + k0 + 32, Al + 512);
    GLL16(Bg + k0,      Bl);
    GLL16(Bg + k0 + 32, Bl + 512);
    __syncthreads();
    #pragma unroll
    for (int kc=0;kc<2;kc++){
      bf16x8 af[2], bfr[2];
      #pragma unroll
      for (int tm=0;tm<2;tm++) af[tm]  = *(bf16x8*)&As[(wm*2+tm)*1024 + kc*512 + quad*128 + lm*8];
      #pragma unroll
      for (int tn=0;tn<2;tn++) bfr[tn] = *(bf16x8*)&Bs[(wn*2+tn)*1024 + kc*512 + quad*128 + lm*8];
      #pragma unroll
      for (int tm=0;tm<2;tm++)
        #pragma unroll
        for (int tn=0;tn<2;tn++)
          acc[tm][tn] = __builtin_amdgcn_mfma_f32_16x16x32_bf16(af[tm], bfr[tn], acc[tm][tn], 0,0,0);
    }
    __syncthreads();
  }

  #pragma unroll
  for (int tm=0;tm<2;tm++){
    #pragma unroll
    for (int tn=0;tn<2;tn++){
      int col = colBase + wn*32 + tn*16 + lm;
      if (col>=N) continue;
      #pragma unroll
      for (int reg=0;reg<4;reg++){
        int row = rowBase + wm*32 + tm*16 + quad*4 + reg;
        if (row>=M) continue;
        float v = epi(acc[tm][tn][reg], bias, col, act);
        if (rbias) v += rbias[row];
        if (res) v += res[(long long)row*ldr+col];
        if (outbf16==3){
          int gi = sgi[(long long)z*8192 + row];
          long long base = ((long long)z*4096 + gi)*384 + col;
          atomicAdd(&ssum[base], v);
          atomicMax(&smax[base], fkey(v));
          if (col==0) atomicAdd(&scnt[(long long)z*4096 + gi], 1.0f);
        }
        else if (outbf16) outH[(long long)row*ldo+col] = fbf(v);
        else {
          outF[(long long)row*ldo+col] = v;
          if (out2) out2[(long long)row*ldo+col] = fbf(v);
        }
      }
    }
  }
}

// ---------- flash-fused view attention v9 (FROZEN) ----------
// grid: 768 blocks 1-D. id%8 = XCD; each XCD handles 3 (v,b) pairs.
// QK6: [6][8192][768] bf16; Vt6: [24][384][2048] bf16
// maskbits: [6][2048][32] u64; O6: [6][8192][384] bf16
// LDS: K 48KB + P [64][68] + alpha f32[64]. 2 blocks/CU. ~385us.
__global__ __launch_bounds__(256,2)
void flash_view(const short* __restrict__ QK6, const short* __restrict__ Vt6,
                const unsigned long long* __restrict__ maskbits, short* __restrict__ O6)
{
  __shared__ char lds[58112];
  const float scale = 0.05103103630798288f;
  int id = blockIdx.x;
  int xcd = id & 7;
  int j = id >> 3;              // 0..95
  int vb = xcd*3 + (j>>5);      // 0..23
  int qt = j & 31;
  int v = vb >> 2, b = vb & 3;
  int tid=threadIdx.x, w=tid>>6, lane=tid&63, lm=lane&15, quad=lane>>4;

  const short* Qp = QK6 + ((long long)v*8192 + b*2048 + qt*64)*768;
  const short* Kp = QK6 + ((long long)v*8192 + b*2048)*768 + 384;
  const short* Vp = Vt6 + (long long)(v*4+b)*384*2048;
  const unsigned long long* Mb = maskbits + (long long)v*2048*32 + (long long)qt*64*32;
  short* Op = O6 + ((long long)v*8192 + b*2048 + qt*64)*384;

  short* P = (short*)(lds + 49152);
  float* alphaL = (float*)(lds + 57856);

  bf16x8 af[12];
  #pragma unroll
  for (int c=0;c<12;c++)
    af[c] = *(const bf16x8*)(Qp + (long long)(w*16+lm)*768 + c*32 + quad*8);

  float m_i[4], l_i[4];
  #pragma unroll
  for (int r=0;r<4;r++){ m_i[r]=-3.0e38f; l_i[r]=0.f; }
  f32x4 Oacc[4][6] = {};

  for (int kt=0; kt<32; kt++){
    #pragma unroll
    for (int c=0;c<12;c++)
      GLL16(Kp + (long long)(kt*64 + w*16 + lm)*768 + c*32 + quad*8, (short*)(lds + w*12288 + c*1024));
    __syncthreads();  // (a) K visible
    unsigned long long mb[4];
    #pragma unroll
    for (int r=0;r<4;r++)
      mb[r] = Mb[(long long)(w*16+quad*4+r)*32 + kt];
    f32x4 S[4];
    #pragma unroll
    for (int i=0;i<4;i++) S[i] = (f32x4){0.f,0.f,0.f,0.f};
    __builtin_amdgcn_s_setprio(1);
    #pragma unroll
    for (int kc=0;kc<12;kc++){
      #pragma unroll
      for (int ct=0;ct<4;ct++){
        bf16x8 bf = *(bf16x8*)(lds + ct*12288 + kc*1024 + quad*256 + lm*16);
        S[ct] = __builtin_amdgcn_mfma_f32_16x16x32_bf16(af[kc], bf, S[ct], 0,0,0);
      }
    }
    __builtin_amdgcn_s_setprio(0);
    #pragma unroll
    for (int r=0;r<4;r++){
      unsigned long long t = mb[r] >> lm;
      S[0][r] = ((unsigned)t      & 1u) ? S[0][r]*scale : -3.0e38f;
      S[1][r] = ((unsigned)(t>>16)& 1u) ? S[1][r]*scale : -3.0e38f;
      S[2][r] = ((unsigned)(t>>32)& 1u) ? S[2][r]*scale : -3.0e38f;
      S[3][r] = ((unsigned)(t>>48)& 1u) ? S[3][r]*scale : -3.0e38f;
    }
    float alpha[4], mnew[4];
    #pragma unroll
    for (int r=0;r<4;r++){
      float rm = S[0][r];
      #pragma unroll
      for (int ct=1;ct<4;ct++) rm = fmaxf(rm, S[ct][r]);
      #pragma unroll
      for (int o=1;o<16;o<<=1) rm = fmaxf(rm, __shfl_xor(rm, o));
      mnew[r] = fmaxf(m_i[r], rm);
      alpha[r] = __expf(m_i[r]-mnew[r]);
      m_i[r] = mnew[r];
    }
    float rs[4] = {0.f,0.f,0.f,0.f};
    #pragma unroll
    for (int ct=0;ct<4;ct++){
      #pragma unroll
      for (int r=0;r<4;r++){
        float sv = S[ct][r];
        float p = (sv > -1.0e37f) ? __expf(sv - mnew[r]) : 0.f;
        rs[r] += p;
        P[(w*16+quad*4+r)*68 + ct*16 + lm] = fbf(p);
      }
    }
    #pragma unroll
    for (int r=0;r<4;r++){
      #pragma unroll
      for (int o=1;o<16;o<<=1) rs[r] += __shfl_xor(rs[r], o);
      l_i[r] = l_i[r]*alpha[r] + rs[r];
    }
    if (lm==0){
      #pragma unroll
      for (int r=0;r<4;r++) alphaL[w*16+quad*4+r] = alpha[r];
    }
    bf16x8 Vreg[6][2];
    #pragma unroll
    for (int jj=0;jj<6;jj++)
      #pragma unroll
      for (int kk=0;kk<2;kk++)
        Vreg[jj][kk] = *(const bf16x8*)(Vp + (long long)((w*6+jj)*16+lm)*2048 + kt*64 + kk*32 + quad*8);
    __syncthreads();  // (b) P/alpha visible; V landed
    f32x4 am[4];
    #pragma unroll
    for (int m=0;m<4;m++) am[m] = *(f32x4*)&alphaL[m*16 + quad*4];
    #pragma unroll
    for (int m=0;m<4;m++)
      #pragma unroll
      for (int tn=0;tn<6;tn++)
        Oacc[m][tn] *= am[m];
    __builtin_amdgcn_s_setprio(1);
    #pragma unroll
    for (int kk=0;kk<2;kk++){
      bf16x8 ap[4];
      #pragma unroll
      for (int m=0;m<4;m++) ap[m] = *(bf16x8*)&P[(m*16+lm)*68 + kk*32 + quad*8];
      #pragma unroll
      for (int tn=0;tn<6;tn++){
        #pragma unroll
        for (int m=0;m<4;m++)
          Oacc[m][tn] = __builtin_amdgcn_mfma_f32_16x16x32_bf16(ap[m], Vreg[tn][kk], Oacc[m][tn], 0,0,0);
      }
    }
    __builtin_amdgcn_s_setprio(0);
  }

  __syncthreads();
  if (lm==0){
    #pragma unroll
    for (int r=0;r<4;r++) alphaL[w*16+quad*4+r] = l_i[r];
  }
  __syncthreads();
  f32x4 lv[4];
  #pragma unroll
  for (int m=0;m<4;m++) lv[m] = *(f32x4*)&alphaL[m*16 + quad*4];
  #pragma unroll
  for (int m=0;m<4;m++){
    #pragma unroll
    for (int tn=0;tn<6;tn++){
      #pragma unroll
      for (int reg=0;reg<4;reg++){
        Op[(long long)(m*16+quad*4+reg)*384 + (w*6+tn)*16 + lm] = fbf(Oacc[m][tn][reg] / lv[m][reg]);
      }
    }
  }
}

// ---------- flash-fused inner attention v5: KVBLK=128 ----------
__global__ __launch_bounds__(256,3)
void flash_inner(const short* __restrict__ QKV, const short* __restrict__ Vt,
                 short* __restrict__ O)
{
  __shared__ char lds[33536];
  int id = blockIdx.x;
  int xcd = id & 7;
  int j = id >> 3;              // 0..98
  int bh = xcd*3 + j/33;        // 0..23
  int qt = j%33;
  int b=bh/6, h=bh-b*6;
  int tid=threadIdx.x, w=tid>>6, lane=tid&63, lm=lane&15, quad=lane>>4;

  const short* Qb = QKV + (long long)b*2049*1152 + h*64;
  const short* Kb = Qb + 384;
  const short* Vtp = Vt + (long long)bh*64*2176;
  short* Op = O + ((long long)b*2049 + qt*64)*384 + h*64;

  short* P = (short*)(lds + 16384);
  float* alphaL = (float*)(lds + 33280);

  int qr = min(qt*64 + w*16 + lm, 2048);
  bf16x8 af[2];
  #pragma unroll
  for (int c=0;c<2;c++)
    af[c] = *(const bf16x8*)(Qb + (long long)qr*1152 + c*32 + quad*8);

  float m_i[4], l_i[4];
  #pragma unroll
  for (int r=0;r<4;r++){ m_i[r]=-3.0e38f; l_i[r]=0.f; }
  f32x4 Oacc[4] = {};

  #pragma unroll
  for (int h2=0;h2<2;h2++){
    int kr0 = min((w*2+h2)*16 + lm, 2048);
    #pragma unroll
    for (int c=0;c<2;c++)
      GLL16(Kb + (long long)kr0*1152 + c*32 + quad*8, (short*)(lds + (w*2+h2)*2048 + c*1024));
  }

  for (int kt=0; kt<17; kt++){
    __syncthreads();  // (a)
    f32x4 S[8];
    #pragma unroll
    for (int i=0;i<8;i++) S[i] = (f32x4){0.f,0.f,0.f,0.f};
    __builtin_amdgcn_s_setprio(1);
    #pragma unroll
    for (int kc=0;kc<2;kc++){
      #pragma unroll
      for (int ct=0;ct<8;ct++){
        bf16x8 bf = *(bf16x8*)(lds + ct*2048 + kc*1024 + quad*256 + lm*16);
        S[ct] = __builtin_amdgcn_mfma_f32_16x16x32_bf16(af[kc], bf, S[ct], 0,0,0);
      }
    }
    __builtin_amdgcn_s_setprio(0);
    #pragma unroll
    for (int ct=0;ct<8;ct++){
      int scol = kt*128 + ct*16 + lm;
      bool ok = scol <= 2048;
      #pragma unroll
      for (int r=0;r<4;r++) S[ct][r] = ok ? S[ct][r]*0.125f : -3.0e38f;
    }
    float alpha[4], mnew[4];
    #pragma unroll
    for (int r=0;r<4;r++){
      float rm = S[0][r];
      #pragma unroll
      for (int ct=1;ct<8;ct++) rm = fmaxf(rm, S[ct][r]);
      #pragma unroll
      for (int o=1;o<16;o<<=1) rm = fmaxf(rm, __shfl_xor(rm, o));
      mnew[r] = fmaxf(m_i[r], rm);
      alpha[r] = __expf(m_i[r]-mnew[r]);
      m_i[r] = mnew[r];
    }
    float rs[4] = {0.f,0.f,0.f,0.f};
    #pragma unroll
    for (int ct=0;ct<8;ct++){
      #pragma unroll
      for (int r=0;r<4;r++){
        float sv = S[ct][r];
        float p = (sv > -1.0e37f) ? __expf(sv - mnew[r]) : 0.f;
        rs[r] += p;
        P[(w*16+quad*4+r)*132 + ct*16 + lm] = fbf(p);
      }
    }
    #pragma unroll
    for (int r=0;r<4;r++){
      #pragma unroll
      for (int o=1;o<16;o<<=1) rs[r] += __shfl_xor(rs[r], o);
      l_i[r] = l_i[r]*alpha[r] + rs[r];
    }
    if (lm==0){
      #pragma unroll
      for (int r=0;r<4;r++) alphaL[w*16+quad*4+r] = alpha[r];
    }
    bf16x8 Vreg[4];
    #pragma unroll
    for (int kk=0;kk<4;kk++)
      Vreg[kk] = *(const bf16x8*)(Vtp + (long long)(w*16+lm)*2176 + kt*128 + kk*32 + quad*8);
    __syncthreads();  // (b)
    if (kt < 16){
      #pragma unroll
      for (int h2=0;h2<2;h2++){
        int krn = min((kt+1)*128 + (w*2+h2)*16 + lm, 2048);
        #pragma unroll
        for (int c=0;c<2;c++)
          GLL16(Kb + (long long)krn*1152 + c*32 + quad*8, (short*)(lds + (w*2+h2)*2048 + c*1024));
      }
    }
    f32x4 am[4];
    #pragma unroll
    for (int m=0;m<4;m++) am[m] = *(f32x4*)&alphaL[m*16 + quad*4];
    #pragma unroll
    for (int m=0;m<4;m++) Oacc[m] *= am[m];
    __builtin_amdgcn_s_setprio(1);
    #pragma unroll
    for (int kk=0;kk<4;kk++){
      bf16x8 ap[4];
      #pragma unroll
      for (int m=0;m<4;m++) ap[m] = *(bf16x8*)&P[(m*16+lm)*132 + kk*32 + quad*8];
      #pragma unroll
      for (int m=0;m<4;m++)
        Oacc[m] = __builtin_amdgcn_mfma_f32_16x16x32_bf16(ap[m], Vreg[kk], Oacc[m], 0,0,0);
    }
    __builtin_amdgcn_s_setprio(0);
  }

  __syncthreads();
  if (lm==0){
    #pragma unroll
    for (int r=0;r<4;r++) alphaL[w*16+quad*4+r] = l_i[r];
  }
  __syncthreads();
  f32x4 lv[4];
  #pragma unroll
  for (int m=0;m<4;m++) lv[m] = *(f32x4*)&alphaL[m*16 + quad*4];
  #pragma unroll
  for (int m=0;m<4;m++){
    #pragma unroll
    for (int reg=0;reg<4;reg++){
      int row = qt*64 + m*16 + quad*4 + reg;
      if (row < 2049)
        Op[(long long)(m*16+quad*4+reg)*384 + w*16 + lm] = fbf(Oacc[m][reg] / lv[m][reg]);
    }
  }
}

// ---------- LayerNorm (fp32 in -> bf16 out), C=384 ----------
__global__ __launch_bounds__(128)
void ln_bf16_kernel(const float* __restrict__ in, const float* __restrict__ g,
                    const float* __restrict__ bt, short* __restrict__ out)
{
  long long row = blockIdx.x;
  const float* p = in + row*384;
  int tid = threadIdx.x;
  float v0=p[tid], v1=p[tid+128], v2=p[tid+256];
  float s = v0+v1+v2;
  float ss = v0*v0+v1*v1+v2*v2;
  __shared__ float r1[2], r2[2];
  s = wsum(s); ss = wsum(ss);
  int wid=tid>>6, lane=tid&63;
  if (lane==0){ r1[wid]=s; r2[wid]=ss; }
  __syncthreads();
  float mean=(r1[0]+r1[1])*(1.f/384.f);
  float var =(r2[0]+r2[1])*(1.f/384.f)-mean*mean;
  float rstd=rsqrtf(var+1e-5f);
  short* o = out + row*384;
  o[tid]     = fbf((v0-mean)*rstd*g[tid]+bt[tid]);
  o[tid+128] = fbf((v1-mean)*rstd*g[tid+128]+bt[tid+128]);
  o[tid+256] = fbf((v2-mean)*rstd*g[tid+256]+bt[tid+256]);
}

// ---------- normalize-only LN (fp32 in -> bf16 n = (x-mu)*rstd), C=384 ----------
__global__ __launch_bounds__(128)
void ln_norm_kernel(const float* __restrict__ in, short* __restrict__ out)
{
  long long row = blockIdx.x;
  const float* p = in + row*384;
  int tid = threadIdx.x;
  float v0=p[tid], v1=p[tid+128], v2=p[tid+256];
  float s = v0+v1+v2;
  float ss = v0*v0+v1*v1+v2*v2;
  __shared__ float r1[2], r2[2];
  s = wsum(s); ss = wsum(ss);
  int wid=tid>>6, lane=tid&63;
  if (lane==0){ r1[wid]=s; r2[wid]=ss; }
  __syncthreads();
  float mean=(r1[0]+r1[1])*(1.f/384.f);
  float var =(r2[0]+r2[1])*(1.f/384.f)-mean*mean;
  float rstd=rsqrtf(var+1e-5f);
  short* o = out + row*384;
  o[tid]     = fbf((v0-mean)*rstd);
  o[tid+128] = fbf((v1-mean)*rstd);
  o[tid+256] = fbf((v2-mean)*rstd);
}

// ---------- bias2[v][n] = sum_k norm3_b[v][k] * a1_qkv_w[v][k][n] ----------
__global__ __launch_bounds__(128)
void bias2_kernel(const float* __restrict__ W, const float* __restrict__ b6,
                  float* __restrict__ bias2)
{
  int n = blockIdx.x*128 + threadIdx.x;   // 0..1151
  int v = blockIdx.y;
  const float* Wv = W + (long long)v*384*1152;
  const float* bv = b6 + v*384;
  float acc = 0.f;
  for (int k=0;k<384;k++) acc += bv[k] * Wv[(long long)k*1152 + n];
  bias2[(long long)v*1152 + n] = acc;
}

// ---------- tiled transpose+convert: fp32 [R,C] -> bf16 [C, ldout]; optional per-input-row scale ----------
__global__ __launch_bounds__(256)
void tconv_kernel(const float* __restrict__ in, int ldin, long long sIn, long long sIn2, int zmod,
                  int R, int C, short* __restrict__ out, int ldout, long long sOut,
                  const float* __restrict__ scale, long long sScale)
{
  __shared__ float tile[32][33];
  int z = blockIdx.z;
  const float* ip = in + (long long)(z/zmod)*sIn + (long long)(z%zmod)*sIn2;
  short* op = out + (long long)z*sOut;
  const float* sc = scale ? (scale + (long long)z*sScale) : nullptr;
  int r0 = blockIdx.x*32;
  int c0 = blockIdx.y*32;
  int tx = threadIdx.x&31, ty = threadIdx.x>>5;
  #pragma unroll
  for (int i=0;i<4;i++){
    int r = r0 + ty + i*8, c = c0 + tx;
    float v = (r<R && c<C) ? ip[(long long)r*ldin + c] : 0.f;
    if (sc && r<R) v *= sc[r];
    tile[ty+i*8][tx] = v;
  }
  __syncthreads();
  #pragma unroll
  for (int i=0;i<4;i++){
    int oc = c0 + ty + i*8;
    int orr = r0 + tx;
    if (oc<C && orr<ldout) op[(long long)oc*ldout + orr] = fbf(tile[tx][ty+i*8]);
  }
}

// ---------- tiled transpose: bf16 [R,C] -> bf16 [C, ldout] ----------
__global__ __launch_bounds__(256)
void tconv16_kernel(const short* __restrict__ in, int ldin, long long sIn, long long sIn2, int zmod,
                    int R, int C, short* __restrict__ out, int ldout, long long sOut)
{
  __shared__ short tile[32][34];
  int z = blockIdx.z;
  const short* ip = in + (long long)(z/zmod)*sIn + (long long)(z%zmod)*sIn2;
  short* op = out + (long long)z*sOut;
  int r0 = blockIdx.x*32;
  int c0 = blockIdx.y*32;
  int tx = threadIdx.x&31, ty = threadIdx.x>>5;
  #pragma unroll
  for (int i=0;i<4;i++){
    int r = r0 + ty + i*8, c = c0 + tx;
    tile[ty+i*8][tx] = (r<R && c<C) ? ip[(long long)r*ldin + c] : (short)0;
  }
  __syncthreads();
  #pragma unroll
  for (int i=0;i<4;i++){
    int oc = c0 + ty + i*8;
    int orr = r0 + tx;
    if (oc<C && orr<ldout) op[(long long)oc*ldout + orr] = tile[tx][ty+i*8];
  }
}

// ---------- fused residual + split + phase-2 cluster scatter ----------
__global__ void ew_fuse_kernel(const float* __restrict__ x1, const float* __restrict__ ffn,
                               const float* __restrict__ ada,
                               const int* __restrict__ cluster,
                               float* __restrict__ fsum, unsigned* __restrict__ fmax,
                               float* __restrict__ cnt,
                               float* __restrict__ ptsb, float* __restrict__ out){
  long long i=(long long)blockIdx.x*256+threadIdx.x;
  if (i >= 8196ll*384) return;
  float v = x1[i] + ffn[i] + 0.5f*ada[i];
  long long row = i/384; int c = (int)(i - row*384);
  long long b = row/2049; long long g = row - b*2049;
  if (g == 0){ out[b*2049*384 + c] = v; return; }
  long long n = b*2048 + (g-1);
  ptsb[n*384 + c] = v;
  int s = cluster[n];
  atomicAdd(&fsum[(long long)s*384 + c], v);
  atomicMax(&fmax[(long long)s*384 + c], fkey(v));
  if (c==0) atomicAdd(&cnt[s], 1.0f);
}

// ---------- cell = bn_gelu(max + mean), z-batched ----------
__global__ __launch_bounds__(128)
void cell_kernel(const float* __restrict__ fsum, const unsigned* __restrict__ fmax,
                 const float* __restrict__ cnt,
                 const float* __restrict__ g, const float* __restrict__ bb,
                 const float* __restrict__ m, const float* __restrict__ v,
                 float* __restrict__ out, long long zSum, long long zCnt, long long zP)
{
  int s = blockIdx.x, z = blockIdx.y;
  fsum += (long long)z*zSum; fmax += (long long)z*zSum; cnt += (long long)z*zCnt;
  g += (long long)z*zP; bb += (long long)z*zP; m += (long long)z*zP; v += (long long)z*zP;
  out += (long long)z*zSum;
  float cn = cnt[s];
  float denom = fmaxf(cn, 1.f);
  int tid = threadIdx.x;
  #pragma unroll
  for (int k=0;k<3;k++){
    int c = tid + k*128;
    float mx = (cn>0.f) ? fdec(fmax[(long long)s*384+c]) : 0.f;
    float t = mx + fsum[(long long)s*384+c]/denom;
    t = (t - m[c])*rsqrtf(v[c]+1e-5f)*g[c] + bb[c];
    out[(long long)s*384+c] = geluf(t);
  }
}

// ---------- final cosine-sim weighted combine: 384 threads, view-parallel ----------
__global__ __launch_bounds__(384)
void combine_kernel(const float* __restrict__ pts, const float* __restrict__ cell3,
                    const int* __restrict__ cluster, const float* __restrict__ cell2,
                    const int* __restrict__ gidx, float* __restrict__ out)
{
  int n = blockIdx.x;
  int tid = threadIdx.x;
  int w = tid>>6, lane = tid&63;
  __shared__ float sdot[6], ssq[6], sn3s;
  __shared__ int soff[6];
  const float* x3 = cell3 + (long long)cluster[n]*384;
  int gi = gidx[(long long)w*8192 + n];
  const float* r = cell2 + ((long long)w*4096 + gi)*384;
  float d=0.f, s2=0.f, q3=0.f;
  #pragma unroll
  for (int k=0;k<6;k++){
    int c = lane + k*64;
    float a = r[c], x = x3[c];
    d += a*x; s2 += a*a; q3 += x*x;
  }
  d = wsum(d); s2 = wsum(s2); q3 = wsum(q3);
  if (lane==0){ sdot[w]=d; ssq[w]=s2; soff[w]=gi; if (w==0) sn3s=q3; }
  __syncthreads();
  float sn3 = sqrtf(sn3s);
  float sims[6]; float ssumv=0.f;
  #pragma unroll
  for (int i=0;i<6;i++){
    float nrm = sqrtf(ssq[i])*sn3;
    float s = (sdot[i]/fmaxf(nrm,1e-8f) + 1.f)*0.5f;
    sims[i]=s; ssumv+=s;
  }
  int c = tid;
  float acc=0.f;
  #pragma unroll
  for (int i=0;i<6;i++){
    const float* rr = cell2 + ((long long)i*4096 + soff[i])*384;
    acc += (sims[i]/ssumv)*rr[c];
  }
  int b = n>>11, gp = n&2047;
  out[((long long)(b*2049 + 1 + gp))*384 + c] = pts[(long long)n*384+c] + 0.5f*acc;
}

// ---------- host helpers ----------
static inline void launch_gemm16b(hipStream_t s, const short* A,int lda,long long sA,
  const short* B,int ldb,long long sB, const float* bias, long long sBias,
  const float* res,int ldr,long long sR, void* out,int ldo,long long sO,int outbf16,
  int M,int N,int K,int act,int nz,int KS)
{
  dim3 g((N+XBN-1)/XBN,(M+XBM-1)/XBM,(unsigned)(nz*KS));
  hipLaunchKernelGGL(gemm_bf16_big,g,dim3(256),0,s,
    A,lda,sA,B,ldb,sB,bias,sBias,res,ldr,sR,out,ldo,sO,outbf16,M,N,K,act,KS);
}
static inline void launch_gemm16s(hipStream_t s, const short* A,int lda,long long sA,int aDiv,
  const short* B,int ldb,long long sB,int bMod, const float* bias, long long sBias,
  const float* rbias, long long sRbias,
  const float* res,int ldr,long long sR, void* out,int ldo,long long sO,int outbf16,
  int M,int N,int K,int act,int nz, short* out2=nullptr,
  const int* sgi=nullptr, float* ssum=nullptr, unsigned* smax=nullptr, float* scnt=nullptr)
{
  dim3 g((N+63)/64,(M+63)/64,(unsigned)nz);
  hipLaunchKernelGGL(gemm_bf16_s,g,dim3(256),0,s,
    A,lda,sA,aDiv,B,ldb,sB,bMod,bias,sBias,rbias,sRbias,res,ldr,sR,out,ldo,sO,outbf16,M,N,K,act,out2,
    sgi,ssum,smax,scnt);
}
static inline void launch_tconv(hipStream_t s, const float* in,int ldin,long long sIn,long long sIn2,int zmod,
  int R,int C, short* out,int ldout,long long sOut,int nz,
  const float* scale=nullptr, long long sScale=0)
{
  dim3 g((ldout+31)/32,(C+31)/32,(unsigned)nz);
  hipLaunchKernelGGL(tconv_kernel,g,dim3(256),0,s, in,ldin,sIn,sIn2,zmod,R,C,out,ldout,sOut,scale,sScale);
}
static inline void launch_tconv16(hipStream_t s, const short* in,int ldin,long long sIn,long long sIn2,int zmod,
  int R,int C, short* out,int ldout,long long sOut,int nz)
{
  dim3 g((ldout+31)/32,(C+31)/32,(unsigned)nz);
  hipLaunchKernelGGL(tconv16_kernel,g,dim3(256),0,s, in,ldin,sIn,sIn2,zmod,R,C,out,ldout,sOut);
}

extern "C" void kernel_launch(void* const* d_in, const int* in_sizes, int n_in,
                              void* d_out, int out_size, void* d_ws, size_t ws_size,
                              hipStream_t stream)
{
  const float* x       = (const float*)d_in[0];
  const float* norm1_g = (const float*)d_in[2];
  const float* norm1_b = (const float*)d_in[3];
  const float* qkv_w   = (const float*)d_in[4];
  const float* proj_w  = (const float*)d_in[5];
  const float* proj_b  = (const float*)d_in[6];
  const float* norm2_g = (const float*)d_in[7];
  const float* norm2_b = (const float*)d_in[8];
  const float* fc1_w   = (const float*)d_in[9];
  const float* fc1_b   = (const float*)d_in[10];
  const float* fc2_w   = (const float*)d_in[11];
  const float* fc2_b   = (const float*)d_in[12];
  const float* ada1_w  = (const float*)d_in[13];
  const float* ada1_b  = (const float*)d_in[14];
  const float* ada2_w  = (const float*)d_in[15];
  const float* ada2_b  = (const float*)d_in[16];
  const float* bn3_g   = (const float*)d_in[17];
  const float* bn3_b   = (const float*)d_in[18];
  const float* bn3_m   = (const float*)d_in[19];
  const float* bn3_v   = (const float*)d_in[20];
  const float* bn2_g   = (const float*)d_in[21];
  const float* bn2_b   = (const float*)d_in[22];
  const float* bn2_m   = (const float*)d_in[23];
  const float* bn2_v   = (const float*)d_in[24];
  const float* norm3_g = (const float*)d_in[25];
  const float* norm3_b = (const float*)d_in[26];
  const float* a1_qkv_w  = (const float*)d_in[27];
  const float* a1_proj_w = (const float*)d_in[28];
  const float* a1_proj_b = (const float*)d_in[29];
  const void*  maskp     = d_in[30];
  const int*   cluster   = (const int*)d_in[33];
  const int*   fgi       = (const int*)d_in[34];
  float* out = (float*)d_out;

  // ---- workspace ----
  size_t off = 0;
  char* wsb = (char*)d_ws;
  auto alloc = [&](size_t bytes)->void*{
    void* p = wsb + off;
    off += (bytes + 255) & ~(size_t)255;
    return p;
  };
  // persistent
  short*    bufHh = (short*)alloc(8196ll*384*2);
  float*    ptsb  = (float*)alloc(8192ll*384*4);
  float*    cnt   = (float*)alloc(1024*4);            // cnt+fsum+fmaxe contiguous (one memset)
  float*    fsum  = (float*)alloc(1024ll*384*4);
  unsigned* fmaxe = (unsigned*)alloc(1024ll*384*4);
  float*    cell3 = (float*)alloc(1024ll*384*4);
  unsigned char* maskb = (unsigned char*)alloc(6ll*2048*2048);  // reused: bit-packed u64
  float*    gc6   = (float*)alloc(6ll*4096*4);
  float*    bias2 = (float*)alloc(6ll*1152*4);        // folded LN beta @ W per view
  short*    qkvT  = (short*)alloc(1152ll*384*2);
  short*    projT = (short*)alloc(384ll*384*2);
  short*    fc1T  = (short*)alloc(1536ll*384*2);
  short*    fc2T  = (short*)alloc(384ll*1536*2);
  short*    ada1T = (short*)alloc(96ll*384*2);
  short*    ada2T = (short*)alloc(384ll*128*2);       // K padded 96->128 (zero-filled)
  short*    a1qkvT  = (short*)alloc(6ll*1152*384*2);  // scaled by norm3_g (LN gamma folded)
  short*    a1projT = (short*)alloc(6ll*384*384*2);
  int*      flag  = (int*)alloc(256);
  // arena: A0 [0,75.5M) + A1 [75.5M,151M) + A2 [151M,188.75M)
  char* arena = (char*)alloc(188743680);
  char* A0 = arena;
  char* A1 = arena + 75497472;
  char* A2 = arena + 150994944;
  // phase-1 overlay
  short* bufQh = (short*)(A0 + 0);            // 8196x1152 bf16 (18.9M)
  float* bufO  = (float*)(A0 + 20971520);     // 8196x384 f32 (12.6M)
  short* bufOh = (short*)(A0 + 35651584);     // 8196x384 bf16 (6.3M)
  short* bufAh = (short*)(A0 + 44040192);     // 8196x128 bf16 (2.1M, K-padded)
  float* bufX  = (float*)(A0 + 46399488);     // 8196x384 f32
  float* bufAda= (float*)(A0 + 0);            // ada2 out (aliases bufQh after qkv dead)
  short* Vt_i  = (short*)(A1 + 0);            // 24x64x2176 bf16 (6.7M)
  short* bufTh = (short*)(A1 + 8388608);      // fc1 out 8196x1536 bf16 (25.2M)
  // view-phase overlay
  short* QK6   = (short*)(A0 + 0);            // 6x8192x768 bf16 (75.5M)
  short* Vt6   = (short*)(A1 + 0);            // 24x384x2048 bf16 (37.7M)
  short* O6    = (short*)(A2 + 0);            // 6x8192x384 bf16 (37.7M)
  short* nbuf  = (short*)(A2 + 0);            // normalized pts 8192x384 bf16 (6.3M; dead before flash writes O6)
  // post-flash overlay (A1: gsum6+gmaxe6 contiguous => one memset)
  float* gsum6 = (float*)(A1 + 0);            // 6x4096x384 f32 (37.7M)
  unsigned* gmaxe6 = (unsigned*)(A1 + 37748736); // 6x4096x384 u32 (37.7M)
  float* cell2 = (float*)(A0 + 0);            // 6x4096x384 f32 (QK6 dead after flash)

  unsigned long long* maskbits = (unsigned long long*)maskb;

  // ---- mask bit packing (dtype from in_sizes: byte mask = 25165824 B) ----
  {
    int mode = (in_sizes[30] == 6*2048*2048) ? 1 : 0;
    long long nOut = 6ll*2048*32;
    mask_bits_kernel<<<dim3((unsigned)((nOut+255)/256)),dim3(256),0,stream>>>(maskp, maskbits, nOut, mode);
  }

  // ---- weight transposes (fp32 [K,N] -> bf16 [N,K]) ----
  launch_tconv(stream, qkv_w, 1152, 0,0,1, 384,1152, qkvT, 384, 0, 1);
  launch_tconv(stream, proj_w, 384, 0,0,1, 384,384,  projT, 384, 0, 1);
  launch_tconv(stream, fc1_w, 1536, 0,0,1, 384,1536, fc1T, 384, 0, 1);
  launch_tconv(stream, fc2_w, 384,  0,0,1, 1536,384, fc2T, 1536, 0, 1);
  launch_tconv(stream, ada1_w, 96,  0,0,1, 384,96,   ada1T, 384, 0, 1);
  launch_tconv(stream, ada2_w, 384, 0,0,1, 96,384,   ada2T, 128, 0, 1);   // ldout=128 zero-pads k 96..127
  // a1qkvT scaled by norm3_g (LN gamma folded into weight)
  launch_tconv(stream, a1_qkv_w, 1152, 384ll*1152,0,1, 384,1152, a1qkvT, 384, 1152ll*384, 6,
               norm3_g, 384);
  launch_tconv(stream, a1_proj_w, 384, 384ll*384,0,1, 384,384,  a1projT, 384, 384ll*384, 6);
  // bias2[v][n] = norm3_b[v] @ a1_qkv_w[v]  (LN beta folded)
  bias2_kernel<<<dim3(9,6),128,0,stream>>>(a1_qkv_w, norm3_b, bias2);

  // ---- phase 1: transformer block ----
  ln_bf16_kernel<<<8196,128,0,stream>>>(x, norm1_g, norm1_b, bufHh);
  launch_gemm16b(stream, bufHh,384,0, qkvT,384,0, nullptr,0, nullptr,0,0,
                 bufQh,1152,0,1, 8196,1152,384, 0, 1,1);
  // V^T for inner attention, zero-padded to 2176 cols (17 x KVBLK=128)
  launch_tconv16(stream, bufQh + 768, 1152, 2049ll*1152, 64, 6, 2049, 64, Vt_i, 2176, 64ll*2176, 24);
  flash_inner<<<dim3(792),256,0,stream>>>(bufQh, Vt_i, bufOh);
  launch_gemm16s(stream, bufOh,384,0,1, projT,384,0,0, proj_b,0, nullptr,0, x,384,0,
                 bufX,384,0,0, 8196,384,384, 0, 1);
  ln_bf16_kernel<<<8196,128,0,stream>>>(bufX, norm2_g, norm2_b, bufHh);
  launch_gemm16b(stream, bufHh,384,0, fc1T,384,0, fc1_b,0, nullptr,0,0,
                 bufTh,1536,0,1, 8196,1536,384, 1, 1,1);
  // fc2 writes f32 (bufO) AND bf16 (bufOh)
  launch_gemm16s(stream, bufTh,1536,0,1, fc2T,1536,0,0, fc2_b,0, nullptr,0, nullptr,0,0,
                 bufO,384,0,0, 8196,384,1536, 0, 1, bufOh);
  // ada1: out ldo=128 (K-pad for ada2); pad cols pre-zeroed
  hipMemsetAsync(bufAh, 0, 8196ll*128*2, stream);
  launch_gemm16s(stream, bufOh,384,0,1, ada1T,384,0,0, ada1_b,0, nullptr,0, nullptr,0,0,
                 bufAh,128,0,1, 8196,96,384, 2, 1);
  launch_gemm16s(stream, bufAh,128,0,1, ada2T,128,0,0, ada2_b,0, nullptr,0, nullptr,0,0,
                 bufAda,384,0,0, 8196,384,128, 0, 1);
  // zero cnt+fsum+fmaxe (contiguous) BEFORE fused scatter
  hipMemsetAsync(cnt, 0, 4096 + 2*1572864, stream);
  ew_fuse_kernel<<<dim3((unsigned)((8196ll*384+255)/256)),256,0,stream>>>(
      bufX, bufO, bufAda, cluster, fsum, fmaxe, cnt, ptsb, out);

  // ---- phase 2: cell3 ----
  cell_kernel<<<dim3(1024,1),128,0,stream>>>(fsum, fmaxe, cnt, bn3_g,bn3_b,bn3_m,bn3_v, cell3, 0,0,0);

  // ---- phase 3a: normalize once; per-view LN folded into weights/bias2 ----
  ln_norm_kernel<<<8192,128,0,stream>>>(ptsb, nbuf);
  // QK6 = n @ W'[:,0:768] + bias2[v][0:768]  (A shared across views: sA=0)
  launch_gemm16b(stream, nbuf,384,0, a1qkvT,384,1152ll*384,
                 bias2,1152, nullptr,0,0, QK6,768,8192ll*768,1, 8192,768,384, 0, 6,1);
  // Vt6[z=v*4+b][d][t] = sum_k W'[k][768+d] n[b-chunk t][k] + bias2[v][768+d]  (row-bias)
  launch_gemm16s(stream, a1qkvT + 768ll*384,384,1152ll*384,4,
                 nbuf,384,2048ll*384,4, nullptr,0, bias2 + 768,1152, nullptr,0,0,
                 Vt6,2048,384ll*2048,1, 384,2048,384, 0, 24);

  // ---- phase 3b: fused flash attention for all 24 (v,b), XCD-swizzled ----
  flash_view<<<dim3(768),256,0,stream>>>(QK6, Vt6, maskbits, O6);

  // ---- phase 3c: a1proj GEMM with fused grid scatter ----
  hipMemsetAsync(gsum6, 0, 2ll*37748736, stream);   // gsum6+gmaxe6 contiguous
  hipMemsetAsync(gc6, 0, 6ll*4096*4, stream);
  launch_gemm16s(stream, O6,384,8192ll*384,1, a1projT,384,384ll*384,0,
                 a1_proj_b,384, nullptr,0, ptsb,384,0,
                 nullptr,384,0,3, 8192,384,384, 0, 6, nullptr,
                 fgi, gsum6, gmaxe6, gc6);
  cell_kernel<<<dim3(4096,6),128,0,stream>>>(gsum6, gmaxe6, gc6,
      bn2_g, bn2_b, bn2_m, bn2_v, cell2, 4096ll*384, 4096, 384);

  // ---- phase 4: combine ----
  combine_kernel<<<8192,384,0,stream>>>(ptsb, cell3, cluster, cell2, fgi, out);
}

// Round 13
// 1384.818 us; speedup vs baseline: 1.0345x; 1.0345x over previous
//
#include <hip/hip_runtime.h>
#include <math.h>

typedef short bf16x8 __attribute__((ext_vector_type(8)));
typedef float f32x4 __attribute__((ext_vector_type(4)));

#define GLL16(g, l) \
  __builtin_amdgcn_global_load_lds((__attribute__((address_space(1))) const unsigned int*)(g), \
                                   (__attribute__((address_space(3))) unsigned int*)(l), 16, 0, 0)

// ---------- helpers ----------
__device__ __forceinline__ float wsum(float v){
  #pragma unroll
  for (int o=32;o;o>>=1) v += __shfl_xor(v,o);
  return v;
}
__device__ __forceinline__ float geluf(float x){
  return 0.5f*x*(1.0f+erff(x*0.7071067811865475f));
}
__device__ __forceinline__ short fbf(float f){
  unsigned u = __float_as_uint(f);
  unsigned r = (u + 0x7fffu + ((u>>16)&1u)) >> 16;
  return (short)r;
}
__device__ __forceinline__ float bff(short s){
  return __uint_as_float(((unsigned)(unsigned short)s)<<16);
}
__device__ __forceinline__ unsigned fkey(float f){
  unsigned b=__float_as_uint(f);
  return (b&0x80000000u)? ~b : (b|0x80000000u);
}
__device__ __forceinline__ float fdec(unsigned k){
  unsigned b=(k&0x80000000u)? (k&0x7fffffffu) : ~k;
  return __uint_as_float(b);
}

// ---------- mask bit packing (dtype decided on HOST via in_sizes) ----------
__global__ void mask_bits_kernel(const void* __restrict__ m, unsigned long long* __restrict__ mb,
                                 long long nOut, int mode){
  long long i = (long long)blockIdx.x*256 + threadIdx.x;
  if (i>=nOut) return;
  unsigned long long bits = 0;
  if (mode){ // byte input
    const unsigned long long* p = (const unsigned long long*)((const unsigned char*)m + i*64);
    #pragma unroll
    for (int k=0;k<8;k++){
      unsigned long long v = p[k];
      #pragma unroll
      for (int b=0;b<8;b++)
        bits |= (unsigned long long)(((v>>(b*8))&0xffull)!=0) << (k*8+b);
    }
  } else { // int input
    const int4* p = (const int4*)((const int*)m + i*64);
    #pragma unroll
    for (int k=0;k<16;k++){
      int4 v = p[k];
      bits |= (unsigned long long)(v.x!=0) << (k*4+0);
      bits |= (unsigned long long)(v.y!=0) << (k*4+1);
      bits |= (unsigned long long)(v.z!=0) << (k*4+2);
      bits |= (unsigned long long)(v.w!=0) << (k*4+3);
    }
  }
  mb[i] = bits;
}

__device__ __forceinline__ float epi(float v, const float* bias, int col, int act){
  if (bias) v += bias[col];
  if (act==1) v = geluf(v);
  else if (act==2) v = v*(1.f/(1.f+__expf(-1.702f*v)));
  return v;
}

// ---------- bf16 MFMA GEMM, 128x128 tile, BK=32 ----------
#define XBM 128
#define XBN 128
#define XBK 32
__global__ __launch_bounds__(256)
void gemm_bf16_big(const short* __restrict__ A, int lda, long long sA,
                   const short* __restrict__ B, int ldb, long long sB,
                   const float* __restrict__ bias, long long sBias,
                   const float* __restrict__ res, int ldr, long long sR,
                   void* __restrict__ out, int ldo, long long sO, int outbf16,
                   int M, int N, int K, int act, int KS)
{
  __shared__ short As[XBM*XBK];
  __shared__ short Bs[XBN*XBK];
  int zz = blockIdx.z;
  int z = zz / KS, ks = zz - z*KS;
  A += (long long)z*sA; B += (long long)z*sB;
  if (res) res += (long long)z*sR;
  if (bias) bias += (long long)z*sBias;
  float* outF = (float*)out + (long long)z*sO;
  short* outH = (short*)out + (long long)z*sO;

  int tid = threadIdx.x;
  int rowBase = blockIdx.y*XBM;
  int colBase = blockIdx.x*XBN;

  int Kc = ((K + KS*XBK - 1)/(KS*XBK))*XBK;
  int kbeg = ks*Kc;
  int kend = min(K, kbeg+Kc);
  if (kbeg >= kend) return;

  int w = tid>>6;
  int lane = tid&63;
  int lm = lane&15, quad = lane>>4;
  int waveM = w>>1, waveN = w&1;

  int arow0 = min(rowBase + w*32 + lm,      M-1);
  int arow1 = min(rowBase + w*32 + 16 + lm, M-1);
  int brow0 = min(colBase + w*32 + lm,      N-1);
  int brow1 = min(colBase + w*32 + 16 + lm, N-1);
  const short* Ag0 = A + (long long)arow0*lda + quad*8;
  const short* Ag1 = A + (long long)arow1*lda + quad*8;
  const short* Bg0 = B + (long long)brow0*ldb + quad*8;
  const short* Bg1 = B + (long long)brow1*ldb + quad*8;
  short* Al0 = &As[(w*2+0)*512];
  short* Al1 = &As[(w*2+1)*512];
  short* Bl0 = &Bs[(w*2+0)*512];
  short* Bl1 = &Bs[(w*2+1)*512];

  f32x4 acc[4][4] = {};

  for (int k0=kbeg; k0<kend; k0+=XBK){
    GLL16(Ag0 + k0, Al0);
    GLL16(Ag1 + k0, Al1);
    GLL16(Bg0 + k0, Bl0);
    GLL16(Bg1 + k0, Bl1);
    __syncthreads();
    bf16x8 af[4], bfr[4];
    #pragma unroll
    for (int tm=0;tm<4;tm++) af[tm]  = *(bf16x8*)&As[(waveM*4+tm)*512 + quad*128 + lm*8];
    #pragma unroll
    for (int tn=0;tn<4;tn++) bfr[tn] = *(bf16x8*)&Bs[(waveN*4+tn)*512 + quad*128 + lm*8];
    #pragma unroll
    for (int tm=0;tm<4;tm++)
      #pragma unroll
      for (int tn=0;tn<4;tn++)
        acc[tm][tn] = __builtin_amdgcn_mfma_f32_16x16x32_bf16(af[tm], bfr[tn], acc[tm][tn], 0,0,0);
    __syncthreads();
  }

  #pragma unroll
  for (int tm=0;tm<4;tm++){
    #pragma unroll
    for (int tn=0;tn<4;tn++){
      int col = colBase + waveN*64 + tn*16 + lm;
      if (col>=N) continue;
      #pragma unroll
      for (int reg=0;reg<4;reg++){
        int row = rowBase + waveM*64 + tm*16 + quad*4 + reg;
        if (row>=M) continue;
        float v = acc[tm][tn][reg];
        if (KS>1){ atomicAdd(&outF[(long long)row*ldo+col], v); continue; }
        v = epi(v, bias, col, act);
        if (res) v += res[(long long)row*ldr+col];
        if (outbf16) outH[(long long)row*ldo+col] = fbf(v);
        else         outF[(long long)row*ldo+col] = v;
      }
    }
  }
}

// ---------- bf16 MFMA GEMM, 64x64 tile, BK=64 (half the barriers of BK=32) ----------
// K must be a multiple of 64 (ada chain is padded to K=128).
// outbf16==3: scatter epilogue (segment sum/max/count) — out not written
// out2 (optional): secondary bf16 copy of the f32 output (fuses the cvt pass)
// aDiv: A advances by sA every aDiv z-slices (weight reuse across batch)
__global__ __launch_bounds__(256)
void gemm_bf16_s(const short* __restrict__ A, int lda, long long sA, int aDiv,
                 const short* __restrict__ B, int ldb, long long sB,
                 const float* __restrict__ bias, long long sBias,
                 const float* __restrict__ res, int ldr, long long sR,
                 void* __restrict__ out, int ldo, long long sO, int outbf16,
                 int M, int N, int K, int act, short* __restrict__ out2,
                 const int* __restrict__ sgi, float* __restrict__ ssum,
                 unsigned* __restrict__ smax, float* __restrict__ scnt)
{
  __shared__ short As[64*64];   // [4 row-groups][2 k-halves][512] lane-order
  __shared__ short Bs[64*64];
  int z = blockIdx.z;
  A += (long long)(z/aDiv)*sA; B += (long long)z*sB;
  if (res) res += (long long)z*sR;
  if (bias) bias += (long long)z*sBias;
  float* outF = (float*)out + (long long)z*sO;
  short* outH = (short*)out + (long long)z*sO;

  int tid = threadIdx.x;
  int rowBase = blockIdx.y*64;
  int colBase = blockIdx.x*64;

  int w = tid>>6;
  int lane = tid&63;
  int lm = lane&15, quad = lane>>4;
  int wm = w>>1, wn = w&1;

  int arow = min(rowBase + w*16 + lm, M-1);
  int brow = min(colBase + w*16 + lm, N-1);
  const short* Ag = A + (long long)arow*lda + quad*8;
  const short* Bg = B + (long long)brow*ldb + quad*8;
  short* Al = &As[w*1024];
  short* Bl = &Bs[w*1024];

  f32x4 acc[2][2] = {};

  for (int k0=0; k0<K; k0+=64){
    GLL16(Ag + k0,      Al);
    GLL16(Ag + k0 + 32, Al + 512);
    GLL16(Bg + k0,      Bl);
    GLL16(Bg + k0 + 32, Bl + 512);
    __syncthreads();
    #pragma unroll
    for (int kc=0;kc<2;kc++){
      bf16x8 af[2], bfr[2];
      #pragma unroll
      for (int tm=0;tm<2;tm++) af[tm]  = *(bf16x8*)&As[(wm*2+tm)*1024 + kc*512 + quad*128 + lm*8];
      #pragma unroll
      for (int tn=0;tn<2;tn++) bfr[tn] = *(bf16x8*)&Bs[(wn*2+tn)*1024 + kc*512 + quad*128 + lm*8];
      #pragma unroll
      for (int tm=0;tm<2;tm++)
        #pragma unroll
        for (int tn=0;tn<2;tn++)
          acc[tm][tn] = __builtin_amdgcn_mfma_f32_16x16x32_bf16(af[tm], bfr[tn], acc[tm][tn], 0,0,0);
    }
    __syncthreads();
  }

  #pragma unroll
  for (int tm=0;tm<2;tm++){
    #pragma unroll
    for (int tn=0;tn<2;tn++){
      int col = colBase + wn*32 + tn*16 + lm;
      if (col>=N) continue;
      #pragma unroll
      for (int reg=0;reg<4;reg++){
        int row = rowBase + wm*32 + tm*16 + quad*4 + reg;
        if (row>=M) continue;
        float v = epi(acc[tm][tn][reg], bias, col, act);
        if (res) v += res[(long long)row*ldr+col];
        if (outbf16==3){
          int gi = sgi[(long long)z*8192 + row];
          long long base = ((long long)z*4096 + gi)*384 + col;
          atomicAdd(&ssum[base], v);
          atomicMax(&smax[base], fkey(v));
          if (col==0) atomicAdd(&scnt[(long long)z*4096 + gi], 1.0f);
        }
        else if (outbf16) outH[(long long)row*ldo+col] = fbf(v);
        else {
          outF[(long long)row*ldo+col] = v;
          if (out2) out2[(long long)row*ldo+col] = fbf(v);
        }
      }
    }
  }
}

// ---------- flash-fused view attention v9 (FROZEN): v5 structure + bit-packed mask + setprio ----------
// grid: 768 blocks 1-D. id%8 = XCD; each XCD handles 3 (v,b) pairs.
// QK6: [6][8192][768] bf16; Vt6: [24][384][2048] bf16
// maskbits: [6][2048][32] u64; O6: [6][8192][384] bf16
// LDS: K 48KB + P [64][68] + alpha f32[64]. 2 blocks/CU. ~385us.
__global__ __launch_bounds__(256,2)
void flash_view(const short* __restrict__ QK6, const short* __restrict__ Vt6,
                const unsigned long long* __restrict__ maskbits, short* __restrict__ O6)
{
  __shared__ char lds[58112];
  const float scale = 0.05103103630798288f;
  int id = blockIdx.x;
  int xcd = id & 7;
  int j = id >> 3;              // 0..95
  int vb = xcd*3 + (j>>5);      // 0..23
  int qt = j & 31;
  int v = vb >> 2, b = vb & 3;
  int tid=threadIdx.x, w=tid>>6, lane=tid&63, lm=lane&15, quad=lane>>4;

  const short* Qp = QK6 + ((long long)v*8192 + b*2048 + qt*64)*768;
  const short* Kp = QK6 + ((long long)v*8192 + b*2048)*768 + 384;
  const short* Vp = Vt6 + (long long)(v*4+b)*384*2048;
  const unsigned long long* Mb = maskbits + (long long)v*2048*32 + (long long)qt*64*32;
  short* Op = O6 + ((long long)v*8192 + b*2048 + qt*64)*384;

  short* P = (short*)(lds + 49152);
  float* alphaL = (float*)(lds + 57856);

  // Q A-frags direct global->reg (wave w owns q-rows w*16..w*16+16)
  bf16x8 af[12];
  #pragma unroll
  for (int c=0;c<12;c++)
    af[c] = *(const bf16x8*)(Qp + (long long)(w*16+lm)*768 + c*32 + quad*8);

  float m_i[4], l_i[4];
  #pragma unroll
  for (int r=0;r<4;r++){ m_i[r]=-3.0e38f; l_i[r]=0.f; }
  f32x4 Oacc[4][6] = {};

  for (int kt=0; kt<32; kt++){
    // ---- stage K (64x384): wave w stages rows w*16..+16
    #pragma unroll
    for (int c=0;c<12;c++)
      GLL16(Kp + (long long)(kt*64 + w*16 + lm)*768 + c*32 + quad*8, (short*)(lds + w*12288 + c*1024));
    __syncthreads();  // (a) K visible
    // ---- mask prefetch: 4 u64 words (covers 64 cols x 4 rows), covered by S MFMAs
    unsigned long long mb[4];
    #pragma unroll
    for (int r=0;r<4;r++)
      mb[r] = Mb[(long long)(w*16+quad*4+r)*32 + kt];
    // ---- S: Q(16x384) @ K(64x384)^T
    f32x4 S[4];
    #pragma unroll
    for (int i=0;i<4;i++) S[i] = (f32x4){0.f,0.f,0.f,0.f};
    __builtin_amdgcn_s_setprio(1);
    #pragma unroll
    for (int kc=0;kc<12;kc++){
      #pragma unroll
      for (int ct=0;ct<4;ct++){
        bf16x8 bf = *(bf16x8*)(lds + ct*12288 + kc*1024 + quad*256 + lm*16);
        S[ct] = __builtin_amdgcn_mfma_f32_16x16x32_bf16(af[kc], bf, S[ct], 0,0,0);
      }
    }
    __builtin_amdgcn_s_setprio(0);
    // ---- mask + scale (bit ct*16+lm of mb[r])
    #pragma unroll
    for (int r=0;r<4;r++){
      unsigned long long t = mb[r] >> lm;
      S[0][r] = ((unsigned)t      & 1u) ? S[0][r]*scale : -3.0e38f;
      S[1][r] = ((unsigned)(t>>16)& 1u) ? S[1][r]*scale : -3.0e38f;
      S[2][r] = ((unsigned)(t>>32)& 1u) ? S[2][r]*scale : -3.0e38f;
      S[3][r] = ((unsigned)(t>>48)& 1u) ? S[3][r]*scale : -3.0e38f;
    }
    // ---- online softmax for wave's 16 q-rows
    float alpha[4], mnew[4];
    #pragma unroll
    for (int r=0;r<4;r++){
      float rm = S[0][r];
      #pragma unroll
      for (int ct=1;ct<4;ct++) rm = fmaxf(rm, S[ct][r]);
      #pragma unroll
      for (int o=1;o<16;o<<=1) rm = fmaxf(rm, __shfl_xor(rm, o));
      mnew[r] = fmaxf(m_i[r], rm);
      alpha[r] = __expf(m_i[r]-mnew[r]);
      m_i[r] = mnew[r];
    }
    float rs[4] = {0.f,0.f,0.f,0.f};
    #pragma unroll
    for (int ct=0;ct<4;ct++){
      #pragma unroll
      for (int r=0;r<4;r++){
        float sv = S[ct][r];
        float p = (sv > -1.0e37f) ? __expf(sv - mnew[r]) : 0.f;
        rs[r] += p;
        P[(w*16+quad*4+r)*68 + ct*16 + lm] = fbf(p);
      }
    }
    #pragma unroll
    for (int r=0;r<4;r++){
      #pragma unroll
      for (int o=1;o<16;o<<=1) rs[r] += __shfl_xor(rs[r], o);
      l_i[r] = l_i[r]*alpha[r] + rs[r];
    }
    if (lm==0){
      #pragma unroll
      for (int r=0;r<4;r++) alphaL[w*16+quad*4+r] = alpha[r];
    }
    // ---- V prefetch to regs (latency hidden inside barrier (b) drain)
    bf16x8 Vreg[6][2];
    #pragma unroll
    for (int jj=0;jj<6;jj++)
      #pragma unroll
      for (int kk=0;kk<2;kk++)
        Vreg[jj][kk] = *(const bf16x8*)(Vp + (long long)((w*6+jj)*16+lm)*2048 + kt*64 + kk*32 + quad*8);
    __syncthreads();  // (b) P/alpha visible; V landed
    // ---- rescale Oacc
    f32x4 am[4];
    #pragma unroll
    for (int m=0;m<4;m++) am[m] = *(f32x4*)&alphaL[m*16 + quad*4];
    #pragma unroll
    for (int m=0;m<4;m++)
      #pragma unroll
      for (int tn=0;tn<6;tn++)
        Oacc[m][tn] *= am[m];
    // ---- PV: P(64x64, LDS) @ V(64x384, regs) — wave's 6 tn for all rows
    __builtin_amdgcn_s_setprio(1);
    #pragma unroll
    for (int kk=0;kk<2;kk++){
      bf16x8 ap[4];
      #pragma unroll
      for (int m=0;m<4;m++) ap[m] = *(bf16x8*)&P[(m*16+lm)*68 + kk*32 + quad*8];
      #pragma unroll
      for (int tn=0;tn<6;tn++){
        #pragma unroll
        for (int m=0;m<4;m++)
          Oacc[m][tn] = __builtin_amdgcn_mfma_f32_16x16x32_bf16(ap[m], Vreg[tn][kk], Oacc[m][tn], 0,0,0);
      }
    }
    __builtin_amdgcn_s_setprio(0);
  }

  __syncthreads();
  if (lm==0){
    #pragma unroll
    for (int r=0;r<4;r++) alphaL[w*16+quad*4+r] = l_i[r];
  }
  __syncthreads();
  f32x4 lv[4];
  #pragma unroll
  for (int m=0;m<4;m++) lv[m] = *(f32x4*)&alphaL[m*16 + quad*4];
  #pragma unroll
  for (int m=0;m<4;m++){
    #pragma unroll
    for (int tn=0;tn<6;tn++){
      #pragma unroll
      for (int reg=0;reg<4;reg++){
        Op[(long long)(m*16+quad*4+reg)*384 + (w*6+tn)*16 + lm] = fbf(Oacc[m][tn][reg] / lv[m][reg]);
      }
    }
  }
}

// ---------- flash-fused inner attention v5: KVBLK=128 ----------
// grid 792 blocks 1-D: id%8 = XCD; each XCD handles 3 (b,h) pairs.
// QKV = bufQh [4][2049][1152]; Vt = Vt_i [24][64][2176] (V^T, zero-padded to 2176)
// O = bufOh [4*2049][384]  (bf16)
// LDS: K 16KB + P [64][132] + alpha f32[64]
__global__ __launch_bounds__(256,3)
void flash_inner(const short* __restrict__ QKV, const short* __restrict__ Vt,
                 short* __restrict__ O)
{
  __shared__ char lds[33536];
  int id = blockIdx.x;
  int xcd = id & 7;
  int j = id >> 3;              // 0..98
  int bh = xcd*3 + j/33;        // 0..23
  int qt = j%33;
  int b=bh/6, h=bh-b*6;
  int tid=threadIdx.x, w=tid>>6, lane=tid&63, lm=lane&15, quad=lane>>4;

  const short* Qb = QKV + (long long)b*2049*1152 + h*64;
  const short* Kb = Qb + 384;
  const short* Vtp = Vt + (long long)bh*64*2176;
  short* Op = O + ((long long)b*2049 + qt*64)*384 + h*64;

  short* P = (short*)(lds + 16384);
  float* alphaL = (float*)(lds + 33280);

  int qr = min(qt*64 + w*16 + lm, 2048);
  bf16x8 af[2];
  #pragma unroll
  for (int c=0;c<2;c++)
    af[c] = *(const bf16x8*)(Qb + (long long)qr*1152 + c*32 + quad*8);

  float m_i[4], l_i[4];
  #pragma unroll
  for (int r=0;r<4;r++){ m_i[r]=-3.0e38f; l_i[r]=0.f; }
  f32x4 Oacc[4] = {};

  // ---- prologue: stage K tile 0 (128 rows x 64 cols; wave w stages row-groups w*2, w*2+1)
  #pragma unroll
  for (int h2=0;h2<2;h2++){
    int kr0 = min((w*2+h2)*16 + lm, 2048);
    #pragma unroll
    for (int c=0;c<2;c++)
      GLL16(Kb + (long long)kr0*1152 + c*32 + quad*8, (short*)(lds + (w*2+h2)*2048 + c*1024));
  }

  for (int kt=0; kt<17; kt++){
    __syncthreads();  // (a) K tile kt staged & visible
    f32x4 S[8];
    #pragma unroll
    for (int i=0;i<8;i++) S[i] = (f32x4){0.f,0.f,0.f,0.f};
    __builtin_amdgcn_s_setprio(1);
    #pragma unroll
    for (int kc=0;kc<2;kc++){
      #pragma unroll
      for (int ct=0;ct<8;ct++){
        bf16x8 bf = *(bf16x8*)(lds + ct*2048 + kc*1024 + quad*256 + lm*16);
        S[ct] = __builtin_amdgcn_mfma_f32_16x16x32_bf16(af[kc], bf, S[ct], 0,0,0);
      }
    }
    __builtin_amdgcn_s_setprio(0);
    #pragma unroll
    for (int ct=0;ct<8;ct++){
      int scol = kt*128 + ct*16 + lm;
      bool ok = scol <= 2048;
      #pragma unroll
      for (int r=0;r<4;r++) S[ct][r] = ok ? S[ct][r]*0.125f : -3.0e38f;
    }
    float alpha[4], mnew[4];
    #pragma unroll
    for (int r=0;r<4;r++){
      float rm = S[0][r];
      #pragma unroll
      for (int ct=1;ct<8;ct++) rm = fmaxf(rm, S[ct][r]);
      #pragma unroll
      for (int o=1;o<16;o<<=1) rm = fmaxf(rm, __shfl_xor(rm, o));
      mnew[r] = fmaxf(m_i[r], rm);
      alpha[r] = __expf(m_i[r]-mnew[r]);
      m_i[r] = mnew[r];
    }
    float rs[4] = {0.f,0.f,0.f,0.f};
    #pragma unroll
    for (int ct=0;ct<8;ct++){
      #pragma unroll
      for (int r=0;r<4;r++){
        float sv = S[ct][r];
        float p = (sv > -1.0e37f) ? __expf(sv - mnew[r]) : 0.f;
        rs[r] += p;
        P[(w*16+quad*4+r)*132 + ct*16 + lm] = fbf(p);
      }
    }
    #pragma unroll
    for (int r=0;r<4;r++){
      #pragma unroll
      for (int o=1;o<16;o<<=1) rs[r] += __shfl_xor(rs[r], o);
      l_i[r] = l_i[r]*alpha[r] + rs[r];
    }
    if (lm==0){
      #pragma unroll
      for (int r=0;r<4;r++) alphaL[w*16+quad*4+r] = alpha[r];
    }
    // V prefetch (wave w owns d-cols w*16..+15); last tile reads zero-padded cols
    bf16x8 Vreg[4];
    #pragma unroll
    for (int kk=0;kk<4;kk++)
      Vreg[kk] = *(const bf16x8*)(Vtp + (long long)(w*16+lm)*2176 + kt*128 + kk*32 + quad*8);
    __syncthreads();  // (b) P/alpha visible; V landed; K LDS dead
    // ---- issue K staging for tile kt+1 (drained at next (a), covered by PV)
    if (kt < 16){
      #pragma unroll
      for (int h2=0;h2<2;h2++){
        int krn = min((kt+1)*128 + (w*2+h2)*16 + lm, 2048);
        #pragma unroll
        for (int c=0;c<2;c++)
          GLL16(Kb + (long long)krn*1152 + c*32 + quad*8, (short*)(lds + (w*2+h2)*2048 + c*1024));
      }
    }
    f32x4 am[4];
    #pragma unroll
    for (int m=0;m<4;m++) am[m] = *(f32x4*)&alphaL[m*16 + quad*4];
    #pragma unroll
    for (int m=0;m<4;m++) Oacc[m] *= am[m];
    __builtin_amdgcn_s_setprio(1);
    #pragma unroll
    for (int kk=0;kk<4;kk++){
      bf16x8 ap[4];
      #pragma unroll
      for (int m=0;m<4;m++) ap[m] = *(bf16x8*)&P[(m*16+lm)*132 + kk*32 + quad*8];
      #pragma unroll
      for (int m=0;m<4;m++)
        Oacc[m] = __builtin_amdgcn_mfma_f32_16x16x32_bf16(ap[m], Vreg[kk], Oacc[m], 0,0,0);
    }
    __builtin_amdgcn_s_setprio(0);
  }

  __syncthreads();
  if (lm==0){
    #pragma unroll
    for (int r=0;r<4;r++) alphaL[w*16+quad*4+r] = l_i[r];
  }
  __syncthreads();
  f32x4 lv[4];
  #pragma unroll
  for (int m=0;m<4;m++) lv[m] = *(f32x4*)&alphaL[m*16 + quad*4];
  #pragma unroll
  for (int m=0;m<4;m++){
    #pragma unroll
    for (int reg=0;reg<4;reg++){
      int row = qt*64 + m*16 + quad*4 + reg;
      if (row < 2049)
        Op[(long long)(m*16+quad*4+reg)*384 + w*16 + lm] = fbf(Oacc[m][reg] / lv[m][reg]);
    }
  }
}

// ---------- LayerNorm (fp32 in -> bf16 out), C=384 ----------
__global__ __launch_bounds__(128)
void ln_bf16_kernel(const float* __restrict__ in, const float* __restrict__ g,
                    const float* __restrict__ bt, short* __restrict__ out)
{
  long long row = blockIdx.x;
  const float* p = in + row*384;
  int tid = threadIdx.x;
  float v0=p[tid], v1=p[tid+128], v2=p[tid+256];
  float s = v0+v1+v2;
  float ss = v0*v0+v1*v1+v2*v2;
  __shared__ float r1[2], r2[2];
  s = wsum(s); ss = wsum(ss);
  int wid=tid>>6, lane=tid&63;
  if (lane==0){ r1[wid]=s; r2[wid]=ss; }
  __syncthreads();
  float mean=(r1[0]+r1[1])*(1.f/384.f);
  float var =(r2[0]+r2[1])*(1.f/384.f)-mean*mean;
  float rstd=rsqrtf(var+1e-5f);
  short* o = out + row*384;
  o[tid]     = fbf((v0-mean)*rstd*g[tid]+bt[tid]);
  o[tid+128] = fbf((v1-mean)*rstd*g[tid+128]+bt[tid+128]);
  o[tid+256] = fbf((v2-mean)*rstd*g[tid+256]+bt[tid+256]);
}

// ---------- LN once, write 6 per-view normed copies ----------
__global__ __launch_bounds__(128)
void ln6_kernel(const float* __restrict__ in, const float* __restrict__ g6,
                const float* __restrict__ b6, short* __restrict__ out6)
{
  long long row = blockIdx.x;
  const float* p = in + row*384;
  int tid = threadIdx.x;
  float v0=p[tid], v1=p[tid+128], v2=p[tid+256];
  float s = v0+v1+v2;
  float ss = v0*v0+v1*v1+v2*v2;
  __shared__ float r1[2], r2[2];
  s = wsum(s); ss = wsum(ss);
  int wid=tid>>6, lane=tid&63;
  if (lane==0){ r1[wid]=s; r2[wid]=ss; }
  __syncthreads();
  float mean=(r1[0]+r1[1])*(1.f/384.f);
  float var =(r2[0]+r2[1])*(1.f/384.f)-mean*mean;
  float rstd=rsqrtf(var+1e-5f);
  float n0=(v0-mean)*rstd, n1=(v1-mean)*rstd, n2=(v2-mean)*rstd;
  #pragma unroll
  for (int i=0;i<6;i++){
    const float* g = g6 + i*384;
    const float* bt = b6 + i*384;
    short* o = out6 + (long long)i*8192*384 + row*384;
    o[tid]     = fbf(n0*g[tid]+bt[tid]);
    o[tid+128] = fbf(n1*g[tid+128]+bt[tid+128]);
    o[tid+256] = fbf(n2*g[tid+256]+bt[tid+256]);
  }
}

// ---------- tiled transpose+convert: fp32 [R,C] -> bf16 [C, ldout] (zero-fills pad) ----------
__global__ __launch_bounds__(256)
void tconv_kernel(const float* __restrict__ in, int ldin, long long sIn, long long sIn2, int zmod,
                  int R, int C, short* __restrict__ out, int ldout, long long sOut)
{
  __shared__ float tile[32][33];
  int z = blockIdx.z;
  const float* ip = in + (long long)(z/zmod)*sIn + (long long)(z%zmod)*sIn2;
  short* op = out + (long long)z*sOut;
  int r0 = blockIdx.x*32;
  int c0 = blockIdx.y*32;
  int tx = threadIdx.x&31, ty = threadIdx.x>>5;
  #pragma unroll
  for (int i=0;i<4;i++){
    int r = r0 + ty + i*8, c = c0 + tx;
    tile[ty+i*8][tx] = (r<R && c<C) ? ip[(long long)r*ldin + c] : 0.f;
  }
  __syncthreads();
  #pragma unroll
  for (int i=0;i<4;i++){
    int oc = c0 + ty + i*8;
    int orr = r0 + tx;
    if (oc<C && orr<ldout) op[(long long)oc*ldout + orr] = fbf(tile[tx][ty+i*8]);
  }
}

// ---------- tiled transpose: bf16 [R,C] -> bf16 [C, ldout] ----------
__global__ __launch_bounds__(256)
void tconv16_kernel(const short* __restrict__ in, int ldin, long long sIn, long long sIn2, int zmod,
                    int R, int C, short* __restrict__ out, int ldout, long long sOut)
{
  __shared__ short tile[32][34];
  int z = blockIdx.z;
  const short* ip = in + (long long)(z/zmod)*sIn + (long long)(z%zmod)*sIn2;
  short* op = out + (long long)z*sOut;
  int r0 = blockIdx.x*32;
  int c0 = blockIdx.y*32;
  int tx = threadIdx.x&31, ty = threadIdx.x>>5;
  #pragma unroll
  for (int i=0;i<4;i++){
    int r = r0 + ty + i*8, c = c0 + tx;
    tile[ty+i*8][tx] = (r<R && c<C) ? ip[(long long)r*ldin + c] : (short)0;
  }
  __syncthreads();
  #pragma unroll
  for (int i=0;i<4;i++){
    int oc = c0 + ty + i*8;
    int orr = r0 + tx;
    if (oc<C && orr<ldout) op[(long long)oc*ldout + orr] = tile[tx][ty+i*8];
  }
}

// ---------- fused residual + split + phase-2 cluster scatter ----------
__global__ void ew_fuse_kernel(const float* __restrict__ x1, const float* __restrict__ ffn,
                               const float* __restrict__ ada,
                               const int* __restrict__ cluster,
                               float* __restrict__ fsum, unsigned* __restrict__ fmax,
                               float* __restrict__ cnt,
                               float* __restrict__ ptsb, float* __restrict__ out){
  long long i=(long long)blockIdx.x*256+threadIdx.x;
  if (i >= 8196ll*384) return;
  float v = x1[i] + ffn[i] + 0.5f*ada[i];
  long long row = i/384; int c = (int)(i - row*384);
  long long b = row/2049; long long g = row - b*2049;
  if (g == 0){ out[b*2049*384 + c] = v; return; }
  long long n = b*2048 + (g-1);
  ptsb[n*384 + c] = v;
  int s = cluster[n];
  atomicAdd(&fsum[(long long)s*384 + c], v);
  atomicMax(&fmax[(long long)s*384 + c], fkey(v));
  if (c==0) atomicAdd(&cnt[s], 1.0f);
}

// ---------- cell = bn_gelu(max + mean), z-batched ----------
__global__ __launch_bounds__(128)
void cell_kernel(const float* __restrict__ fsum, const unsigned* __restrict__ fmax,
                 const float* __restrict__ cnt,
                 const float* __restrict__ g, const float* __restrict__ bb,
                 const float* __restrict__ m, const float* __restrict__ v,
                 float* __restrict__ out, long long zSum, long long zCnt, long long zP)
{
  int s = blockIdx.x, z = blockIdx.y;
  fsum += (long long)z*zSum; fmax += (long long)z*zSum; cnt += (long long)z*zCnt;
  g += (long long)z*zP; bb += (long long)z*zP; m += (long long)z*zP; v += (long long)z*zP;
  out += (long long)z*zSum;
  float cn = cnt[s];
  float denom = fmaxf(cn, 1.f);
  int tid = threadIdx.x;
  #pragma unroll
  for (int k=0;k<3;k++){
    int c = tid + k*128;
    float mx = (cn>0.f) ? fdec(fmax[(long long)s*384+c]) : 0.f;
    float t = mx + fsum[(long long)s*384+c]/denom;
    t = (t - m[c])*rsqrtf(v[c]+1e-5f)*g[c] + bb[c];
    out[(long long)s*384+c] = geluf(t);
  }
}

// ---------- final cosine-sim weighted combine: 384 threads, view-parallel ----------
__global__ __launch_bounds__(384)
void combine_kernel(const float* __restrict__ pts, const float* __restrict__ cell3,
                    const int* __restrict__ cluster, const float* __restrict__ cell2,
                    const int* __restrict__ gidx, float* __restrict__ out)
{
  int n = blockIdx.x;
  int tid = threadIdx.x;
  int w = tid>>6, lane = tid&63;
  __shared__ float sdot[6], ssq[6], sn3s;
  __shared__ int soff[6];
  const float* x3 = cell3 + (long long)cluster[n]*384;
  int gi = gidx[(long long)w*8192 + n];
  const float* r = cell2 + ((long long)w*4096 + gi)*384;
  float d=0.f, s2=0.f, q3=0.f;
  #pragma unroll
  for (int k=0;k<6;k++){
    int c = lane + k*64;
    float a = r[c], x = x3[c];
    d += a*x; s2 += a*a; q3 += x*x;
  }
  d = wsum(d); s2 = wsum(s2); q3 = wsum(q3);
  if (lane==0){ sdot[w]=d; ssq[w]=s2; soff[w]=gi; if (w==0) sn3s=q3; }
  __syncthreads();
  float sn3 = sqrtf(sn3s);
  float sims[6]; float ssumv=0.f;
  #pragma unroll
  for (int i=0;i<6;i++){
    float nrm = sqrtf(ssq[i])*sn3;
    float s = (sdot[i]/fmaxf(nrm,1e-8f) + 1.f)*0.5f;
    sims[i]=s; ssumv+=s;
  }
  int c = tid;
  float acc=0.f;
  #pragma unroll
  for (int i=0;i<6;i++){
    const float* rr = cell2 + ((long long)i*4096 + soff[i])*384;
    acc += (sims[i]/ssumv)*rr[c];
  }
  int b = n>>11, gp = n&2047;
  out[((long long)(b*2049 + 1 + gp))*384 + c] = pts[(long long)n*384+c] + 0.5f*acc;
}

// ---------- host helpers ----------
static inline void launch_gemm16b(hipStream_t s, const short* A,int lda,long long sA,
  const short* B,int ldb,long long sB, const float* bias, long long sBias,
  const float* res,int ldr,long long sR, void* out,int ldo,long long sO,int outbf16,
  int M,int N,int K,int act,int nz,int KS)
{
  dim3 g((N+XBN-1)/XBN,(M+XBM-1)/XBM,(unsigned)(nz*KS));
  hipLaunchKernelGGL(gemm_bf16_big,g,dim3(256),0,s,
    A,lda,sA,B,ldb,sB,bias,sBias,res,ldr,sR,out,ldo,sO,outbf16,M,N,K,act,KS);
}
static inline void launch_gemm16s(hipStream_t s, const short* A,int lda,long long sA,int aDiv,
  const short* B,int ldb,long long sB, const float* bias, long long sBias,
  const float* res,int ldr,long long sR, void* out,int ldo,long long sO,int outbf16,
  int M,int N,int K,int act,int nz, short* out2=nullptr,
  const int* sgi=nullptr, float* ssum=nullptr, unsigned* smax=nullptr, float* scnt=nullptr)
{
  dim3 g((N+63)/64,(M+63)/64,(unsigned)nz);
  hipLaunchKernelGGL(gemm_bf16_s,g,dim3(256),0,s,
    A,lda,sA,aDiv,B,ldb,sB,bias,sBias,res,ldr,sR,out,ldo,sO,outbf16,M,N,K,act,out2,
    sgi,ssum,smax,scnt);
}
static inline void launch_tconv(hipStream_t s, const float* in,int ldin,long long sIn,long long sIn2,int zmod,
  int R,int C, short* out,int ldout,long long sOut,int nz)
{
  dim3 g((ldout+31)/32,(C+31)/32,(unsigned)nz);
  hipLaunchKernelGGL(tconv_kernel,g,dim3(256),0,s, in,ldin,sIn,sIn2,zmod,R,C,out,ldout,sOut);
}
static inline void launch_tconv16(hipStream_t s, const short* in,int ldin,long long sIn,long long sIn2,int zmod,
  int R,int C, short* out,int ldout,long long sOut,int nz)
{
  dim3 g((ldout+31)/32,(C+31)/32,(unsigned)nz);
  hipLaunchKernelGGL(tconv16_kernel,g,dim3(256),0,s, in,ldin,sIn,sIn2,zmod,R,C,out,ldout,sOut);
}

extern "C" void kernel_launch(void* const* d_in, const int* in_sizes, int n_in,
                              void* d_out, int out_size, void* d_ws, size_t ws_size,
                              hipStream_t stream)
{
  const float* x       = (const float*)d_in[0];
  const float* norm1_g = (const float*)d_in[2];
  const float* norm1_b = (const float*)d_in[3];
  const float* qkv_w   = (const float*)d_in[4];
  const float* proj_w  = (const float*)d_in[5];
  const float* proj_b  = (const float*)d_in[6];
  const float* norm2_g = (const float*)d_in[7];
  const float* norm2_b = (const float*)d_in[8];
  const float* fc1_w   = (const float*)d_in[9];
  const float* fc1_b   = (const float*)d_in[10];
  const float* fc2_w   = (const float*)d_in[11];
  const float* fc2_b   = (const float*)d_in[12];
  const float* ada1_w  = (const float*)d_in[13];
  const float* ada1_b  = (const float*)d_in[14];
  const float* ada2_w  = (const float*)d_in[15];
  const float* ada2_b  = (const float*)d_in[16];
  const float* bn3_g   = (const float*)d_in[17];
  const float* bn3_b   = (const float*)d_in[18];
  const float* bn3_m   = (const float*)d_in[19];
  const float* bn3_v   = (const float*)d_in[20];
  const float* bn2_g   = (const float*)d_in[21];
  const float* bn2_b   = (const float*)d_in[22];
  const float* bn2_m   = (const float*)d_in[23];
  const float* bn2_v   = (const float*)d_in[24];
  const float* norm3_g = (const float*)d_in[25];
  const float* norm3_b = (const float*)d_in[26];
  const float* a1_qkv_w  = (const float*)d_in[27];
  const float* a1_proj_w = (const float*)d_in[28];
  const float* a1_proj_b = (const float*)d_in[29];
  const void*  maskp     = d_in[30];
  const int*   cluster   = (const int*)d_in[33];
  const int*   fgi       = (const int*)d_in[34];
  float* out = (float*)d_out;

  // ---- workspace ----
  size_t off = 0;
  char* wsb = (char*)d_ws;
  auto alloc = [&](size_t bytes)->void*{
    void* p = wsb + off;
    off += (bytes + 255) & ~(size_t)255;
    return p;
  };
  // persistent
  short*    bufHh = (short*)alloc(8196ll*384*2);
  float*    ptsb  = (float*)alloc(8192ll*384*4);
  float*    cnt   = (float*)alloc(1024*4);            // cnt+fsum+fmaxe contiguous (one memset)
  float*    fsum  = (float*)alloc(1024ll*384*4);
  unsigned* fmaxe = (unsigned*)alloc(1024ll*384*4);
  float*    cell3 = (float*)alloc(1024ll*384*4);
  unsigned char* maskb = (unsigned char*)alloc(6ll*2048*2048);  // reused: bit-packed u64
  float*    gc6   = (float*)alloc(6ll*4096*4);
  short*    qkvT  = (short*)alloc(1152ll*384*2);
  short*    projT = (short*)alloc(384ll*384*2);
  short*    fc1T  = (short*)alloc(1536ll*384*2);
  short*    fc2T  = (short*)alloc(384ll*1536*2);
  short*    ada1T = (short*)alloc(96ll*384*2);
  short*    ada2T = (short*)alloc(384ll*128*2);       // K padded 96->128 (zero-filled)
  short*    a1qkvT  = (short*)alloc(6ll*1152*384*2);
  short*    a1projT = (short*)alloc(6ll*384*384*2);
  int*      flag  = (int*)alloc(256);
  // arena: A0 [0,75.5M) + A1 [75.5M,151M) + A2 [151M,188.75M)
  char* arena = (char*)alloc(188743680);
  char* A0 = arena;
  char* A1 = arena + 75497472;
  char* A2 = arena + 150994944;
  // phase-1 overlay
  short* bufQh = (short*)(A0 + 0);            // 8196x1152 bf16 (18.9M)
  float* bufO  = (float*)(A0 + 20971520);     // 8196x384 f32 (12.6M)
  short* bufOh = (short*)(A0 + 35651584);     // 8196x384 bf16 (6.3M)
  short* bufAh = (short*)(A0 + 44040192);     // 8196x128 bf16 (2.1M, K-padded)
  float* bufX  = (float*)(A0 + 46399488);     // 8196x384 f32 (moved +256KB for bufAh pad)
  float* bufAda= (float*)(A0 + 0);            // ada2 out (aliases bufQh after qkv dead)
  short* Vt_i  = (short*)(A1 + 0);            // 24x64x2176 bf16 (6.7M)
  short* bufTh = (short*)(A1 + 8388608);      // fc1 out 8196x1536 bf16 (25.2M)
  // view-phase overlay
  short* QK6   = (short*)(A0 + 0);            // 6x8192x768 bf16 (75.5M)
  short* Vt6   = (short*)(A1 + 0);            // 24x384x2048 bf16 (37.7M)
  short* O6    = (short*)(A2 + 0);            // 6x8192x384 bf16 (37.7M)
  short* bufHh6= (short*)(A2 + 0);            // ln6 out (aliases O6; dead before flash)
  // post-flash overlay (A1: gsum6+gmaxe6 contiguous => one memset)
  float* gsum6 = (float*)(A1 + 0);            // 6x4096x384 f32 (37.7M)
  unsigned* gmaxe6 = (unsigned*)(A1 + 37748736); // 6x4096x384 u32 (37.7M)
  float* cell2 = (float*)(A0 + 0);            // 6x4096x384 f32 (QK6 dead after flash)

  unsigned long long* maskbits = (unsigned long long*)maskb;

  // ---- mask bit packing (dtype from in_sizes: byte mask = 25165824 B) ----
  {
    int mode = (in_sizes[30] == 6*2048*2048) ? 1 : 0;
    long long nOut = 6ll*2048*32;
    mask_bits_kernel<<<dim3((unsigned)((nOut+255)/256)),dim3(256),0,stream>>>(maskp, maskbits, nOut, mode);
  }

  // ---- weight transposes (fp32 [K,N] -> bf16 [N,K]) ----
  launch_tconv(stream, qkv_w, 1152, 0,0,1, 384,1152, qkvT, 384, 0, 1);
  launch_tconv(stream, proj_w, 384, 0,0,1, 384,384,  projT, 384, 0, 1);
  launch_tconv(stream, fc1_w, 1536, 0,0,1, 384,1536, fc1T, 384, 0, 1);
  launch_tconv(stream, fc2_w, 384,  0,0,1, 1536,384, fc2T, 1536, 0, 1);
  launch_tconv(stream, ada1_w, 96,  0,0,1, 384,96,   ada1T, 384, 0, 1);
  launch_tconv(stream, ada2_w, 384, 0,0,1, 96,384,   ada2T, 128, 0, 1);   // ldout=128 zero-pads k 96..127
  launch_tconv(stream, a1_qkv_w, 1152, 384ll*1152,0,1, 384,1152, a1qkvT, 384, 1152ll*384, 6);
  launch_tconv(stream, a1_proj_w, 384, 384ll*384,0,1, 384,384,  a1projT, 384, 384ll*384, 6);

  // ---- phase 1: transformer block ----
  ln_bf16_kernel<<<8196,128,0,stream>>>(x, norm1_g, norm1_b, bufHh);
  launch_gemm16b(stream, bufHh,384,0, qkvT,384,0, nullptr,0, nullptr,0,0,
                 bufQh,1152,0,1, 8196,1152,384, 0, 1,1);
  // V^T for inner attention, zero-padded to 2176 cols (17 x KVBLK=128)
  launch_tconv16(stream, bufQh + 768, 1152, 2049ll*1152, 64, 6, 2049, 64, Vt_i, 2176, 64ll*2176, 24);
  flash_inner<<<dim3(792),256,0,stream>>>(bufQh, Vt_i, bufOh);
  launch_gemm16s(stream, bufOh,384,0,1, projT,384,0, proj_b,0, x,384,0,
                 bufX,384,0,0, 8196,384,384, 0, 1);
  ln_bf16_kernel<<<8196,128,0,stream>>>(bufX, norm2_g, norm2_b, bufHh);
  launch_gemm16b(stream, bufHh,384,0, fc1T,384,0, fc1_b,0, nullptr,0,0,
                 bufTh,1536,0,1, 8196,1536,384, 1, 1,1);
  // fc2 writes f32 (bufO) AND bf16 (bufOh) — cvt pass fused away
  launch_gemm16s(stream, bufTh,1536,0,1, fc2T,1536,0, fc2_b,0, nullptr,0,0,
                 bufO,384,0,0, 8196,384,1536, 0, 1, bufOh);
  // ada1: out ldo=128 (K-pad for ada2); pad cols pre-zeroed
  hipMemsetAsync(bufAh, 0, 8196ll*128*2, stream);
  launch_gemm16s(stream, bufOh,384,0,1, ada1T,384,0, ada1_b,0, nullptr,0,0,
                 bufAh,128,0,1, 8196,96,384, 2, 1);
  launch_gemm16s(stream, bufAh,128,0,1, ada2T,128,0, ada2_b,0, nullptr,0,0,
                 bufAda,384,0,0, 8196,384,128, 0, 1);
  // zero cnt+fsum+fmaxe (contiguous) BEFORE fused scatter
  hipMemsetAsync(cnt, 0, 4096 + 2*1572864, stream);
  // fused: residual -> ptsb/out + phase-2 cluster scatter (sum/max/count)
  ew_fuse_kernel<<<dim3((unsigned)((8196ll*384+255)/256)),256,0,stream>>>(
      bufX, bufO, bufAda, cluster, fsum, fmaxe, cnt, ptsb, out);

  // ---- phase 2: cell3 ----
  cell_kernel<<<dim3(1024,1),128,0,stream>>>(fsum, fmaxe, cnt, bn3_g,bn3_b,bn3_m,bn3_v, cell3, 0,0,0);

  // ---- phase 3a: batched view projections ----
  ln6_kernel<<<8192,128,0,stream>>>(ptsb, norm3_g, norm3_b, bufHh6);
  launch_gemm16b(stream, bufHh6,384,8192ll*384, a1qkvT,384,1152ll*384,
                 nullptr,0, nullptr,0,0, QK6,768,8192ll*768,1, 8192,768,384, 0, 6,1);
  // V^T computed directly: A = V-weight rows (d), B = h rows -> Vt6[z][d][n] coalesced.
  // z = v*4+b (24); A advances per v (aDiv=4).
  launch_gemm16s(stream, a1qkvT + 768ll*384,384,1152ll*384,4,
                 bufHh6,384,2048ll*384, nullptr,0, nullptr,0,0,
                 Vt6,2048,384ll*2048,1, 384,2048,384, 0, 24);

  // ---- phase 3b: fused flash attention for all 24 (v,b), XCD-swizzled ----
  flash_view<<<dim3(768),256,0,stream>>>(QK6, Vt6, maskbits, O6);

  // ---- phase 3c: a1proj GEMM with fused grid scatter ----
  hipMemsetAsync(gsum6, 0, 2ll*37748736, stream);   // gsum6+gmaxe6 contiguous
  hipMemsetAsync(gc6, 0, 6ll*4096*4, stream);
  launch_gemm16s(stream, O6,384,8192ll*384,1, a1projT,384,384ll*384,
                 a1_proj_b,384, ptsb,384,0,
                 nullptr,384,0,3, 8192,384,384, 0, 6, nullptr,
                 fgi, gsum6, gmaxe6, gc6);
  cell_kernel<<<dim3(4096,6),128,0,stream>>>(gsum6, gmaxe6, gc6,
      bn2_g, bn2_b, bn2_m, bn2_v, cell2, 4096ll*384, 4096, 384);

  // ---- phase 4: combine ----
  combine_kernel<<<8192,384,0,stream>>>(ptsb, cell3, cluster, cell2, fgi, out);
}